// Round 8
// baseline (75.572 us; speedup 1.0000x reference)
//
#include <hip/hip_runtime.h>
#include <math.h>

// Problem constants
constexpr int EPG  = 512;     // edges per graph
constexpr int ETOT = 131072;  // total edges

// ws float-region offsets (floats)
constexpr size_t TAB_Q  = 0;
constexpr size_t TAB_K  = 1024;
constexpr size_t TAB_V  = 2048;
constexpr size_t TAB_S  = 3072;   // 4*64
constexpr size_t TAB_LG = 3328;   // 64
constexpr size_t OFF_H2P = 65536; // packed h2 u32 [16384][64]

// ws short-region offsets (shorts), region starts at (short*)(ws + 4096)
constexpr int PK_V_HI   = 0;      // Wv2^T [256][64]
constexpr int PK_V_LO   = 16384;
constexpr int PK_S_HI   = 32768;  // Ws2^T [64][64]
constexpr int PK_S_LO   = 36864;
constexpr int PK_E1T_HI = 40960;
constexpr int PK_E1T_LO = 45056;
constexpr int PK_E1B_HI = 49152;
constexpr int PK_E1B_LO = 53248;
constexpr int PK_M_HI   = 57344;  // per head +4096: pack[m][k] = M~[k][m]
constexpr int PK_M_LO   = 73728;
constexpr int PK_VV_HI  = 90112;  // [16][64] rows h<4 = v~_h, rest 0
constexpr int PK_VV_LO  = 91136;
constexpr int PK_N_HI   = 92160;  // [16][64] rows c<4 = Wn[:,c], rest 0
constexpr int PK_N_LO   = 93184;

typedef short bf16x8 __attribute__((ext_vector_type(8)));
typedef float f32x4  __attribute__((ext_vector_type(4)));

__device__ __forceinline__ short f2bf(float x) {
    unsigned u = __float_as_uint(x);
    u = (u + 0x7fffu + ((u >> 16) & 1u)) >> 16;   // RNE
    return (short)u;
}
__device__ __forceinline__ float bf2f(short h) {
    return __uint_as_float(((unsigned)(unsigned short)h) << 16);
}
__device__ __forceinline__ void splt(float x, short& hi, short& lo) {
    hi = f2bf(x);
    lo = f2bf(x - bf2f(hi));
}
__device__ __forceinline__ unsigned packsplt(float x) {
    short hi, lo; splt(x, hi, lo);
    return ((unsigned)(unsigned short)hi << 16) | (unsigned short)lo;
}

// hi/lo split product: C += Ah*Bh + Ah*Bl + Al*Bh  (error ~2^-17 rel)
__device__ __forceinline__ f32x4 mfma3(bf16x8 ah, bf16x8 al, bf16x8 bh, bf16x8 bl, f32x4 c) {
    c = __builtin_amdgcn_mfma_f32_16x16x32_bf16(ah, bh, c, 0, 0, 0);
    c = __builtin_amdgcn_mfma_f32_16x16x32_bf16(ah, bl, c, 0, 0, 0);
    c = __builtin_amdgcn_mfma_f32_16x16x32_bf16(al, bh, c, 0, 0, 0);
    return c;
}

// fragment from LDS row-major [.][72] bf16: lane row=base+(l&15), k=kb+(l>>4)*8+e
__device__ __forceinline__ bf16x8 ldsfrag(const short* p, int rowb, int kb, int lane) {
    return *(const bf16x8*)&p[(rowb + (lane & 15)) * 72 + kb + ((lane >> 4) << 3)];
}
// fragment from global pack [N][64] bf16
__device__ __forceinline__ bf16x8 gpfrag(const short* p, int colb, int kb, int lane) {
    return *(const bf16x8*)&p[((colb + (lane & 15)) << 6) + kb + ((lane >> 4) << 3)];
}
// unpack 8 consecutive (hi<<16|lo) u32 -> two bf16x8 fragments
__device__ __forceinline__ void unpack8(const unsigned* p, bf16x8& hv, bf16x8& lv) {
    uint4 a = *(const uint4*)p;
    uint4 b = *(const uint4*)(p + 4);
    unsigned u[8] = {a.x, a.y, a.z, a.w, b.x, b.y, b.z, b.w};
    bf16x8 h, l;
    #pragma unroll
    for (int i = 0; i < 8; i++) { h[i] = (short)(u[i] >> 16); l[i] = (short)(u[i] & 0xffffu); }
    hv = h; lv = l;
}

// ---------------------------------------------------------------------------
// k_tabprep: b<112 weight packs; b in [112,128): M~ = WqWk^T/8 (4 blocks/head,
// float4 inner); b in [128,132): v~ packs; b==132: time embedding + layer-1
// class tables + Wn pack + vv zero rows.
// ---------------------------------------------------------------------------
__global__ __launch_bounds__(256) void k_tabprep(
    const int* __restrict__ t_ptr,
    const float* __restrict__ Wt,  const float* __restrict__ bt,
    const float* __restrict__ Wq1, const float* __restrict__ bq1,
    const float* __restrict__ Wk1, const float* __restrict__ bk1,
    const float* __restrict__ Wv1, const float* __restrict__ bv1,
    const float* __restrict__ Ws1, const float* __restrict__ bs1,
    const float* __restrict__ Wq2, const float* __restrict__ bq2,
    const float* __restrict__ Wk2, const float* __restrict__ Wv2,
    const float* __restrict__ Ws2, const float* __restrict__ We1,
    const float* __restrict__ Wn,
    float* __restrict__ ws, short* __restrict__ wsh)
{
    const int t = threadIdx.x, b = blockIdx.x;
    if (b < 112) {   // ---- weight pack path (transposed, bf16 hi/lo) ----
        const float* src; int N; int dhi; int nb;
        if (b < 64)      { src = Wv2;           N = 256; dhi = PK_V_HI;   nb = b; }
        else if (b < 80) { src = Ws2;           N = 64;  dhi = PK_S_HI;   nb = b - 64; }
        else if (b < 96) { src = We1;           N = 64;  dhi = PK_E1T_HI; nb = b - 80; }
        else             { src = We1 + 64 * 64; N = 64;  dhi = PK_E1B_HI; nb = b - 96; }
        int dlo = dhi + N * 64;
        int n = nb * 4 + (t >> 6), kk = t & 63;
        float v = src[(size_t)kk * N + n];
        short hi, lo; splt(v, hi, lo);
        wsh[dhi + n * 64 + kk] = hi;
        wsh[dlo + n * 64 + kk] = lo;
        return;
    }
    if (b < 128) {   // ---- M~ quarter block: head h, m rows m0..m0+16 ----
        int h = (b - 112) >> 2, m0 = ((b - 112) & 3) * 16;
        __shared__ __align__(16) float wq[64][68];
        __shared__ __align__(16) float wk[16][68];
        for (int i = t; i < 1024; i += 256) {
            int r = i >> 4, c4 = (i & 15) * 4;
            *(float4*)&wq[r][c4] = *(const float4*)&Wq2[(size_t)r * 256 + h * 64 + c4];
        }
        {
            int r = t >> 4, c4 = (t & 15) * 4;
            *(float4*)&wk[r][c4] = *(const float4*)&Wk2[(size_t)(m0 + r) * 256 + h * 64 + c4];
        }
        __syncthreads();
        const int m = m0 + (t >> 4), kk0 = (t & 15) * 4;
        const float* wkr = &wk[t >> 4][0];
        for (int kk = kk0; kk < kk0 + 4; kk++) {
            const float* wqr = &wq[kk][0];
            float acc = 0.f;
            #pragma unroll
            for (int a = 0; a < 64; a += 4) {
                float4 qa = *(const float4*)(wqr + a);
                float4 ka = *(const float4*)(wkr + a);
                acc += qa.x * ka.x + qa.y * ka.y + qa.z * ka.z + qa.w * ka.w;
            }
            acc *= 0.125f;
            short hi, lo; splt(acc, hi, lo);
            wsh[PK_M_HI + h * 4096 + m * 64 + kk] = hi;
            wsh[PK_M_LO + h * 4096 + m * 64 + kk] = lo;
        }
        return;
    }
    if (b < 132) {   // ---- v~ = Wk bq /8 per head ----
        int h = b - 128;
        if (t < 64) {
            float acc = 0.f;
            for (int a = 0; a < 64; a++)
                acc += Wk2[(size_t)t * 256 + h * 64 + a] * bq2[h * 64 + a];
            short hi, lo; splt(0.125f * acc, hi, lo);
            wsh[PK_VV_HI + h * 64 + t] = hi;
            wsh[PK_VV_LO + h * 64 + t] = lo;
        }
        return;
    }
    // ---- tables path ----
    __shared__ float se[16], temb[16];
    __shared__ float q1t[4][256], k1t[4][256], v1t[4][256], s1t[4][64];
    if (t < 8) {
        float tv = (float)(*t_ptr) * 0.01f;
        float scale = logf(10000.0f) / 7.0f;
        float e = tv * expf(-(float)t * scale);
        se[t]     = sinf(e);
        se[t + 8] = cosf(e);
    }
    __syncthreads();
    if (t < 16) {
        float acc = bt[t];
        for (int i = 0; i < 16; i++) acc += se[i] * Wt[i * 16 + t];
        temb[t] = acc;
    }
    __syncthreads();
    {
        const int o = t;
        float tq = 0.f, tk = 0.f, tv = 0.f;
        for (int d = 0; d < 16; d++) {
            float td = temb[d];
            tq += td * Wq1[(4 + d) * 256 + o];
            tk += td * Wk1[(4 + d) * 256 + o];
            tv += td * Wv1[(4 + d) * 256 + o];
        }
        for (int c = 0; c < 4; c++) {
            q1t[c][o] = Wq1[c * 256 + o] + tq + bq1[o];
            k1t[c][o] = Wk1[c * 256 + o] + tk + bk1[o];
            v1t[c][o] = Wv1[c * 256 + o] + tv + bv1[o];
        }
        if (o < 64) {
            float ts = 0.f;
            for (int d = 0; d < 16; d++) ts += temb[d] * Ws1[(4 + d) * 64 + o];
            for (int c = 0; c < 4; c++) s1t[c][o] = Ws1[c * 64 + o] + ts + bs1[o];
        }
    }
    __syncthreads();
    for (int idx = t; idx < 1024; idx += 256) {
        int c = idx >> 8, o = idx & 255;
        ws[TAB_Q + idx] = q1t[c][o];
        ws[TAB_K + idx] = k1t[c][o];
        ws[TAB_V + idx] = v1t[c][o];
    }
    ws[TAB_S + t] = s1t[t >> 6][t & 63];
    if (t < 64) {
        int cd = t >> 4, cs = (t >> 2) & 3, h = t & 3;
        float acc = 0.f;
        for (int d = 0; d < 64; d++) acc += q1t[cd][h * 64 + d] * k1t[cs][h * 64 + d];
        ws[TAB_LG + t] = acc * 0.125f;
    }
    // Wn pack [16][64], rows c<4 valid
    for (int idx = t; idx < 1024; idx += 256) {
        int c = idx >> 6, k = idx & 63;
        float v = (c < 4) ? Wn[k * 4 + c] : 0.f;
        short hi, lo; splt(v, hi, lo);
        wsh[PK_N_HI + idx] = hi;
        wsh[PK_N_LO + idx] = lo;
    }
    // vv pack zero rows 4..15
    for (int idx = 256 + t; idx < 1024; idx += 256) {
        wsh[PK_VV_HI + idx] = 0;
        wsh[PK_VV_LO + idx] = 0;
    }
}

// ---------------------------------------------------------------------------
// k_main: grid 512 = (graph, query-row-half), 512 thr, 8 waves, 2 blocks/CU.
// (512,4) pins 2 blocks/CU; rotate-only prefetch proved spill-free at this
// budget (r5). 2 barriers/head; next-head pack loads issued right after B1.
// ---------------------------------------------------------------------------
__global__ __launch_bounds__(512, 4) void k_main(
    const float* __restrict__ x, const int* __restrict__ ei,
    const float* __restrict__ ws, const short* __restrict__ wsh,
    const float* __restrict__ bv, const float* __restrict__ bsk,
    unsigned* __restrict__ h2p)
{
    __shared__ __align__(16) char smem[59008];
    short*    hHi  = (short*)(smem);             // [64][72]
    short*    hLo  = (short*)(smem + 9216);
    short*    VtHi = (short*)(smem + 18432);     // [64][72] (d-major)
    short*    VtLo = (short*)(smem + 27648);
    unsigned* Gst  = (unsigned*)(smem + 36864);  // [32][68] packed hi|lo
    float*    SPf  = (float*)(smem + 45568);     // [32][68] S f32
    char*     Cc   = (char*)(smem + 54272);      // [32][68] u8 counts
    float*    wcol = (float*)(smem + 56448);     // [4][64]
    float*    lgs  = (float*)(smem + 57472);     // 64
    int*      cls  = (int*)(smem + 57728);       // 64
    int*      cnt4 = (int*)(smem + 57984);       // 256
    // setup aliases over Vt region (dead until head-0 phase A)
    float*    v1t  = (float*)(smem + 18432);     // 1024
    float*    s1t  = (float*)(smem + 22528);     // 256

    const int g    = blockIdx.x >> 1;
    const int r0   = (blockIdx.x & 1) * 32;
    const int t    = threadIdx.x;
    const int lane = t & 63, w = t >> 6;
    const int rb   = (w & 1) * 16;               // local row band
    const int cb   = (w >> 1) * 16;              // col band (m / j / d)
    const int db   = (w & 3) * 16;               // Vt: d band
    const int jb0  = (w >> 2) * 32;              // Vt: j bands jb0, jb0+16
    const int lg4  = ((lane >> 4) << 2);
    const int lg8  = ((lane >> 4) << 3);
    const int l15  = lane & 15;
    const int row8 = t >> 3;                     // 0..63 (h1 phase)
    const int d08  = (t & 7) * 8;

    // ---- P0: tables + zero counters ---------------------------------------
    for (int i = t; i < 1024; i += 512) v1t[i] = ws[TAB_V + i];
    if (t < 256) s1t[t] = ws[TAB_S + t];
    if (t < 64)  lgs[t] = ws[TAB_LG + t];
    if (t < 64) {
        const float* xr = x + (size_t)(g * 64 + t) * 4;
        int c = 0;
        if (xr[1] > 0.5f) c = 1;
        if (xr[2] > 0.5f) c = 2;
        if (xr[3] > 0.5f) c = 3;
        cls[t] = c;
    }
    if (t < 256) cnt4[t] = 0;
    for (int i = t; i < 544; i += 512) ((int*)Cc)[i] = 0;
    __syncthreads();

    // ---- P1: edge counts ---------------------------------------------------
    {
        int ge = g * EPG + t;
        int ls = ei[ge] - g * 64;
        int ld = ei[ETOT + ge] - g * 64;
        atomicAdd(&cnt4[ld * 4 + cls[ls]], 1);
        int lr = ld - r0;
        if ((unsigned)lr < 32u) {
            int idx = lr * 68 + ls;
            atomicAdd((int*)(Cc + (idx & ~3)), 1 << ((idx & 3) * 8));
        }
    }
    __syncthreads();

    // ---- P3: h1 with inline per-row alpha (vectorized b128 store) ----------
    {
        int cd = cls[row8];
        int c0 = cnt4[row8 * 4], c1 = cnt4[row8 * 4 + 1],
            c2 = cnt4[row8 * 4 + 2], c3 = cnt4[row8 * 4 + 3];
        float a[16];
        #pragma unroll
        for (int hh = 0; hh < 4; hh++) {
            float l0 = lgs[cd * 16 + hh], l1 = lgs[cd * 16 + 4 + hh],
                  l2 = lgs[cd * 16 + 8 + hh], l3 = lgs[cd * 16 + 12 + hh];
            float m = -1e30f;
            if (c0 > 0) m = fmaxf(m, l0);
            if (c1 > 0) m = fmaxf(m, l1);
            if (c2 > 0) m = fmaxf(m, l2);
            if (c3 > 0) m = fmaxf(m, l3);
            float e0 = (c0 > 0) ? (float)c0 * __expf(l0 - m) : 0.f;
            float e1 = (c1 > 0) ? (float)c1 * __expf(l1 - m) : 0.f;
            float e2 = (c2 > 0) ? (float)c2 * __expf(l2 - m) : 0.f;
            float e3 = (c3 > 0) ? (float)c3 * __expf(l3 - m) : 0.f;
            float den = e0 + e1 + e2 + e3;
            float inv = (den > 0.f) ? 0.25f / den : 0.f;
            a[hh * 4 + 0] = e0 * inv; a[hh * 4 + 1] = e1 * inv;
            a[hh * 4 + 2] = e2 * inv; a[hh * 4 + 3] = e3 * inv;
        }
        bf16x8 vh, vl;
        #pragma unroll
        for (int jj = 0; jj < 8; jj++) {
            int d = d08 + jj;
            float acc = s1t[cd * 64 + d];
            #pragma unroll
            for (int hh = 0; hh < 4; hh++)
                #pragma unroll
                for (int c = 0; c < 4; c++)
                    acc += a[hh * 4 + c] * v1t[c * 256 + hh * 64 + d];
            float o = fmaxf(acc, 0.f);
            short hi, lo; splt(o, hi, lo);
            vh[jj] = hi; vl[jj] = lo;
        }
        *(bf16x8*)&hHi[row8 * 72 + d08] = vh;
        *(bf16x8*)&hLo[row8 * 72 + d08] = vl;
    }
    __syncthreads();

    // ---- cached h1 A-frags (our rows) --------------------------------------
    bf16x8 AhQ0 = ldsfrag(hHi, r0 + rb, 0, lane),  AhQ1 = ldsfrag(hHi, r0 + rb, 32, lane);
    bf16x8 AlQ0 = ldsfrag(hLo, r0 + rb, 0, lane),  AlQ1 = ldsfrag(hLo, r0 + rb, 32, lane);

    // ---- skip projection ---------------------------------------------------
    f32x4 skacc = {0.f, 0.f, 0.f, 0.f};
    {
        bf16x8 sk0h = gpfrag(wsh + PK_S_HI, cb, 0, lane);
        bf16x8 sk0l = gpfrag(wsh + PK_S_LO, cb, 0, lane);
        bf16x8 sk1h = gpfrag(wsh + PK_S_HI, cb, 32, lane);
        bf16x8 sk1l = gpfrag(wsh + PK_S_LO, cb, 32, lane);
        skacc = mfma3(AhQ0, AlQ0, sk0h, sk0l, skacc);
        skacc = mfma3(AhQ1, AlQ1, sk1h, sk1l, skacc);
        float bb = bsk[cb + l15];
        #pragma unroll
        for (int r = 0; r < 4; r++) skacc[r] += bb;
    }

    // ---- wcol via MFMA (waves 0..3; band w*16) -----------------------------
    if (w < 4) {
        bf16x8 vv0h = gpfrag(wsh + PK_VV_HI, 0, 0, lane);
        bf16x8 vv0l = gpfrag(wsh + PK_VV_LO, 0, 0, lane);
        bf16x8 vv1h = gpfrag(wsh + PK_VV_HI, 0, 32, lane);
        bf16x8 vv1l = gpfrag(wsh + PK_VV_LO, 0, 32, lane);
        bf16x8 a0h = ldsfrag(hHi, w * 16, 0, lane),  a1h = ldsfrag(hHi, w * 16, 32, lane);
        bf16x8 a0l = ldsfrag(hLo, w * 16, 0, lane),  a1l = ldsfrag(hLo, w * 16, 32, lane);
        f32x4 wc = {0.f, 0.f, 0.f, 0.f};
        wc = mfma3(a0h, a0l, vv0h, vv0l, wc);
        wc = mfma3(a1h, a1l, vv1h, vv1l, wc);
        if (l15 < 4) {
            #pragma unroll
            for (int r = 0; r < 4; r++)
                wcol[l15 * 64 + w * 16 + lg4 + r] = wc[r];
        }
    }

    // ---- head-0 pack loads (rotated thereafter) ----------------------------
    bf16x8 cm0h = gpfrag(wsh + PK_M_HI, cb, 0, lane);
    bf16x8 cm0l = gpfrag(wsh + PK_M_LO, cb, 0, lane);
    bf16x8 cm1h = gpfrag(wsh + PK_M_HI, cb, 32, lane);
    bf16x8 cm1l = gpfrag(wsh + PK_M_LO, cb, 32, lane);
    bf16x8 cv0h = gpfrag(wsh + PK_V_HI, db, 0, lane);
    bf16x8 cv0l = gpfrag(wsh + PK_V_LO, db, 0, lane);
    bf16x8 cv1h = gpfrag(wsh + PK_V_HI, db, 32, lane);
    bf16x8 cv1l = gpfrag(wsh + PK_V_LO, db, 32, lane);
    float4 cbv  = *(const float4*)&bv[db + lg4];

    // ---- head loop: 2 barriers/head, rotate prefetch -----------------------
    float hacc[4] = {0.f, 0.f, 0.f, 0.f};
    #pragma unroll 1
    for (int h = 0; h < 4; h++) {
        // --- phase A: G (strip) and V^T from prefetched packs ---
        {
            f32x4 ga = {0.f, 0.f, 0.f, 0.f};
            ga = mfma3(AhQ0, AlQ0, cm0h, cm0l, ga);
            ga = mfma3(AhQ1, AlQ1, cm1h, cm1l, ga);
            #pragma unroll
            for (int r = 0; r < 4; r++)
                Gst[(rb + lg4 + r) * 68 + cb + l15] = packsplt(ga[r]);
        }
        {
            bf16x8 hb00h = ldsfrag(hHi, jb0, 0, lane),       hb00l = ldsfrag(hLo, jb0, 0, lane);
            bf16x8 hb01h = ldsfrag(hHi, jb0, 32, lane),      hb01l = ldsfrag(hLo, jb0, 32, lane);
            bf16x8 hb10h = ldsfrag(hHi, jb0 + 16, 0, lane),  hb10l = ldsfrag(hLo, jb0 + 16, 0, lane);
            bf16x8 hb11h = ldsfrag(hHi, jb0 + 16, 32, lane), hb11l = ldsfrag(hLo, jb0 + 16, 32, lane);
            f32x4 vt0 = {0.f, 0.f, 0.f, 0.f}, vt1 = {0.f, 0.f, 0.f, 0.f};
            vt0 = mfma3(cv0h, cv0l, hb00h, hb00l, vt0);
            vt0 = mfma3(cv1h, cv1l, hb01h, hb01l, vt0);
            vt1 = mfma3(cv0h, cv0l, hb10h, hb10l, vt1);
            vt1 = mfma3(cv1h, cv1l, hb11h, hb11l, vt1);
            #pragma unroll
            for (int r = 0; r < 4; r++) {
                int rr = (db + lg4 + r) * 72;
                short hi, lo;
                splt(vt0[r] + cbv[r], hi, lo);
                VtHi[rr + jb0 + l15] = hi;      VtLo[rr + jb0 + l15] = lo;
                splt(vt1[r] + cbv[r], hi, lo);
                VtHi[rr + jb0 + 16 + l15] = hi; VtLo[rr + jb0 + 16 + l15] = lo;
            }
        }
        __syncthreads();   // B1: G, V^T visible

        // --- issue next head's pack loads (hide L2 latency under S+softmax) --
        int hn = (h + 1) & 3;
        const short* pmh = wsh + PK_M_HI + hn * 4096;
        const short* pml = wsh + PK_M_LO + hn * 4096;
        bf16x8 nm0h = gpfrag(pmh, cb, 0, lane),  nm0l = gpfrag(pml, cb, 0, lane);
        bf16x8 nm1h = gpfrag(pmh, cb, 32, lane), nm1l = gpfrag(pml, cb, 32, lane);
        int gc = hn * 64 + db;
        bf16x8 nv0h = gpfrag(wsh + PK_V_HI, gc, 0, lane);
        bf16x8 nv0l = gpfrag(wsh + PK_V_LO, gc, 0, lane);
        bf16x8 nv1h = gpfrag(wsh + PK_V_HI, gc, 32, lane);
        bf16x8 nv1l = gpfrag(wsh + PK_V_LO, gc, 32, lane);
        float4 nbv  = *(const float4*)&bv[gc + lg4];

        // --- phase B: hoist PV B-frags; S = G h1^T ---
        bf16x8 vb0h = ldsfrag(VtHi, cb, 0, lane),  vb0l = ldsfrag(VtLo, cb, 0, lane);
        bf16x8 vb1h = ldsfrag(VtHi, cb, 32, lane), vb1l = ldsfrag(VtLo, cb, 32, lane);
        {
            bf16x8 gh0, gl0, gh1, gl1;
            const unsigned* gp = Gst + (rb + l15) * 68 + lg8;
            unpack8(gp, gh0, gl0);
            unpack8(gp + 32, gh1, gl1);
            bf16x8 sb0h = ldsfrag(hHi, cb, 0, lane),  sb0l = ldsfrag(hLo, cb, 0, lane);
            bf16x8 sb1h = ldsfrag(hHi, cb, 32, lane), sb1l = ldsfrag(hLo, cb, 32, lane);
            f32x4 s = {0.f, 0.f, 0.f, 0.f};
            s = mfma3(gh0, gl0, sb0h, sb0l, s);
            s = mfma3(gh1, gl1, sb1h, sb1l, s);
            #pragma unroll
            for (int r = 0; r < 4; r++)
                SPf[(rb + lg4 + r) * 68 + cb + l15] = s[r];
        }
        __syncthreads();   // B2: S visible

        // --- phase C: in-wave softmax -> P frags -> PV (no trailing barrier:
        // next head's SPf write is gated by B1) ---
        {
            const int lr = rb + l15;
            float sv[16];
            {
                const float* sp = SPf + lr * 68;
                float4 a0 = *(const float4*)(sp + lg8);
                float4 a1 = *(const float4*)(sp + lg8 + 4);
                float4 a2 = *(const float4*)(sp + 32 + lg8);
                float4 a3 = *(const float4*)(sp + 32 + lg8 + 4);
                sv[0]=a0.x; sv[1]=a0.y; sv[2]=a0.z; sv[3]=a0.w;
                sv[4]=a1.x; sv[5]=a1.y; sv[6]=a1.z; sv[7]=a1.w;
                sv[8]=a2.x; sv[9]=a2.y; sv[10]=a2.z; sv[11]=a2.w;
                sv[12]=a3.x; sv[13]=a3.y; sv[14]=a3.z; sv[15]=a3.w;
            }
            int cv[16];
            {
                const unsigned* crow = (const unsigned*)(Cc + lr * 68);
                unsigned c0 = crow[lg8 >> 2], c1 = crow[(lg8 >> 2) + 1];
                unsigned c2 = crow[(32 + lg8) >> 2], c3 = crow[((32 + lg8) >> 2) + 1];
                #pragma unroll
                for (int e = 0; e < 4; e++) {
                    cv[e]      = (c0 >> (e * 8)) & 255;
                    cv[4 + e]  = (c1 >> (e * 8)) & 255;
                    cv[8 + e]  = (c2 >> (e * 8)) & 255;
                    cv[12 + e] = (c3 >> (e * 8)) & 255;
                }
            }
            #pragma unroll
            for (int e = 0; e < 8; e++) {
                sv[e]     += wcol[h * 64 + lg8 + e];
                sv[8 + e] += wcol[h * 64 + 32 + lg8 + e];
            }
            float m = -1e30f;
            #pragma unroll
            for (int e = 0; e < 16; e++) if (cv[e] > 0) m = fmaxf(m, sv[e]);
            m = fmaxf(m, __shfl_xor(m, 16));
            m = fmaxf(m, __shfl_xor(m, 32));
            float den = 0.f; float p[16];
            #pragma unroll
            for (int e = 0; e < 16; e++) {
                p[e] = (cv[e] > 0) ? (float)cv[e] * __expf(sv[e] - m) : 0.f;
                den += p[e];
            }
            den += __shfl_xor(den, 16);
            den += __shfl_xor(den, 32);
            float inv = (den > 0.f) ? 1.f / den : 0.f;
            bf16x8 pa0h, pa0l, pa1h, pa1l;
            #pragma unroll
            for (int e = 0; e < 8; e++) {
                short hi, lo;
                splt(p[e] * inv, hi, lo);      pa0h[e] = hi; pa0l[e] = lo;
                splt(p[8 + e] * inv, hi, lo);  pa1h[e] = hi; pa1l[e] = lo;
            }
            f32x4 pv = {0.f, 0.f, 0.f, 0.f};
            pv = mfma3(pa0h, pa0l, vb0h, vb0l, pv);
            pv = mfma3(pa1h, pa1l, vb1h, vb1l, pv);
            #pragma unroll
            for (int r = 0; r < 4; r++) hacc[r] += pv[r];
        }
        // rotate prefetched packs
        cm0h = nm0h; cm0l = nm0l; cm1h = nm1h; cm1l = nm1l;
        cv0h = nv0h; cv0l = nv0l; cv1h = nv1h; cv1l = nv1l;
        cbv = nbv;
    }

    // ---- h2 = relu(mean_heads + skip) -> packed u32 global -----------------
    #pragma unroll
    for (int r = 0; r < 4; r++) {
        float v = fmaxf(0.25f * hacc[r] + skacc[r], 0.f);
        h2p[(size_t)(g * 64 + r0 + rb + lg4 + r) * 64 + cb + l15] = packsplt(v);
    }
}

// ---------------------------------------------------------------------------
// k_edge: grid 1024 = (graph, row-quarter), 256 thr, 4 waves. Plain
// launch_bounds (register-friendly; the fp32 MLP needs ~100 VGPRs live).
// Node logits via MFMA (PK_N). A own 16 rows; B^T full; fp32 edge MLP.
// ---------------------------------------------------------------------------
__global__ __launch_bounds__(256) void k_edge(
    const short* __restrict__ wsh, const unsigned* __restrict__ h2g,
    const float* __restrict__ bn, const float* __restrict__ be1,
    const float* __restrict__ We2, const float* __restrict__ be2,
    float* __restrict__ out)
{
    __shared__ __align__(16) char smem[39680];
    unsigned* h2P = (unsigned*)(smem);           // [64][68] packed
    float*    Af  = (float*)(smem + 17408);      // [16][68]
    float*    BTf = (float*)(smem + 21760);      // [64][68]
    float*    w2s = (float*)(smem + 39168);      // 128

    const int g  = blockIdx.x >> 2;
    const int i0 = (blockIdx.x & 3) * 16;
    const int t  = threadIdx.x;
    const int lane = t & 63, w = t >> 6;
    const int lg4 = ((lane >> 4) << 2);
    const int lg8 = ((lane >> 4) << 3);
    const int l15 = lane & 15;

    {   // load packed h2 (full graph): 16 u32/thread
        int row = t >> 2, c16 = (t & 3) * 16;
        const unsigned* src = h2g + (size_t)(g * 64 + row) * 64 + c16;
        #pragma unroll
        for (int q = 0; q < 4; q++)
            *(uint4*)&h2P[row * 68 + c16 + q * 4] = *(const uint4*)(src + q * 4);
    }
    if (t < 128) w2s[(t & 1) * 64 + (t >> 1)] = We2[t];
    __syncthreads();

    {   // A (own 16 rows, col band w*16) + node logits (wave 0)
        bf16x8 aq0, lq0, aq1, lq1;
        const unsigned* ap = h2P + (i0 + l15) * 68;
        unpack8(ap + lg8, aq0, lq0);
        unpack8(ap + 32 + lg8, aq1, lq1);
        {
            int colb = w * 16;
            bf16x8 e0h = gpfrag(wsh + PK_E1T_HI, colb, 0, lane),  e0l = gpfrag(wsh + PK_E1T_LO, colb, 0, lane);
            bf16x8 e1h = gpfrag(wsh + PK_E1T_HI, colb, 32, lane), e1l = gpfrag(wsh + PK_E1T_LO, colb, 32, lane);
            f32x4 aa = {0.f, 0.f, 0.f, 0.f};
            aa = mfma3(aq0, lq0, e0h, e0l, aa);
            aa = mfma3(aq1, lq1, e1h, e1l, aa);
            float bev = be1[colb + l15];
            #pragma unroll
            for (int r = 0; r < 4; r++)
                Af[(lg4 + r) * 68 + colb + l15] = aa[r] + bev;
        }
        if (w == 0) {
            bf16x8 n0h = gpfrag(wsh + PK_N_HI, 0, 0, lane),  n0l = gpfrag(wsh + PK_N_LO, 0, 0, lane);
            bf16x8 n1h = gpfrag(wsh + PK_N_HI, 0, 32, lane), n1l = gpfrag(wsh + PK_N_LO, 0, 32, lane);
            f32x4 nl = {0.f, 0.f, 0.f, 0.f};
            nl = mfma3(aq0, lq0, n0h, n0l, nl);
            nl = mfma3(aq1, lq1, n1h, n1l, nl);
            if (l15 < 4) {
                #pragma unroll
                for (int r = 0; r < 4; r++)
                    out[(size_t)(g * 64 + i0 + lg4 + r) * 4 + l15] = nl[r] + bn[l15];
            }
        }
    }
    {   // B^T (full graph): wave w owns rows w*16, loops 4 col bands
        bf16x8 af0, lf0, af1, lf1;
        const unsigned* ap = h2P + (w * 16 + l15) * 68;
        unpack8(ap + lg8, af0, lf0);
        unpack8(ap + 32 + lg8, af1, lf1);
        #pragma unroll
        for (int ct = 0; ct < 4; ct++) {
            int colb = ct * 16;
            bf16x8 b0h = gpfrag(wsh + PK_E1B_HI, colb, 0, lane),  b0l = gpfrag(wsh + PK_E1B_LO, colb, 0, lane);
            bf16x8 b1h = gpfrag(wsh + PK_E1B_HI, colb, 32, lane), b1l = gpfrag(wsh + PK_E1B_LO, colb, 32, lane);
            f32x4 bb = {0.f, 0.f, 0.f, 0.f};
            bb = mfma3(af0, lf0, b0h, b0l, bb);
            bb = mfma3(af1, lf1, b1h, b1l, bb);
            #pragma unroll
            for (int r = 0; r < 4; r++)
                BTf[(colb + l15) * 68 + w * 16 + lg4 + r] = bb[r];
        }
    }
    __syncthreads();

    // edge MLP: wave w -> rows i0 + w*4 .. +4, lane j
    {
        const int j = t & 63;
        float e0[4], e1[4];
        const float cb0 = be2[0], cb1 = be2[1];
        #pragma unroll
        for (int ii = 0; ii < 4; ii++) { e0[ii] = cb0; e1[ii] = cb1; }
        for (int kb = 0; kb < 4; kb++) {
            const int k0 = kb * 16;
            float bj[16], wa[16], wb[16];
            #pragma unroll
            for (int q = 0; q < 16; q++) {
                bj[q] = BTf[(k0 + q) * 68 + j];
                wa[q] = w2s[k0 + q];
                wb[q] = w2s[64 + k0 + q];
            }
            #pragma unroll
            for (int ii = 0; ii < 4; ii++) {
                const float* ar = &Af[(w * 4 + ii) * 68 + k0];
                #pragma unroll
                for (int q = 0; q < 16; q += 4) {
                    float4 a4 = *(const float4*)(ar + q);
                    float s;
                    s = fmaxf(a4.x + bj[q + 0], 0.f); e0[ii] += s * wa[q + 0]; e1[ii] += s * wb[q + 0];
                    s = fmaxf(a4.y + bj[q + 1], 0.f); e0[ii] += s * wa[q + 1]; e1[ii] += s * wb[q + 1];
                    s = fmaxf(a4.z + bj[q + 2], 0.f); e0[ii] += s * wa[q + 2]; e1[ii] += s * wb[q + 2];
                    s = fmaxf(a4.w + bj[q + 3], 0.f); e0[ii] += s * wa[q + 3]; e1[ii] += s * wb[q + 3];
                }
            }
        }
        float2* oe = (float2*)(out + 65536);
        #pragma unroll
        for (int ii = 0; ii < 4; ii++)
            oe[(size_t)(g * 64 + i0 + w * 4 + ii) * 64 + j] = make_float2(e0[ii], e1[ii]);
    }
}

// ---------------------------------------------------------------------------
extern "C" void kernel_launch(void* const* d_in, const int* in_sizes, int n_in,
                              void* d_out, int out_size, void* d_ws, size_t ws_size,
                              hipStream_t stream)
{
    const float* x    = (const float*)d_in[0];
    const int*   ei   = (const int*)d_in[1];
    const int*   tptr = (const int*)d_in[3];
    const float* Wt   = (const float*)d_in[4];
    const float* bt   = (const float*)d_in[5];
    const float* Wq1  = (const float*)d_in[6];
    const float* bq1  = (const float*)d_in[7];
    const float* Wk1  = (const float*)d_in[8];
    const float* bk1  = (const float*)d_in[9];
    const float* Wv1  = (const float*)d_in[10];
    const float* bv1  = (const float*)d_in[11];
    const float* Ws1  = (const float*)d_in[12];
    const float* bs1  = (const float*)d_in[13];
    const float* Wq2  = (const float*)d_in[14];
    const float* bq2  = (const float*)d_in[15];
    const float* Wk2  = (const float*)d_in[16];
    const float* Wv2  = (const float*)d_in[18];
    const float* bv2  = (const float*)d_in[19];
    const float* Ws2  = (const float*)d_in[20];
    const float* bs2  = (const float*)d_in[21];
    const float* Wn   = (const float*)d_in[22];
    const float* bn   = (const float*)d_in[23];
    const float* We1  = (const float*)d_in[24];
    const float* be1  = (const float*)d_in[25];
    const float* We2  = (const float*)d_in[26];
    const float* be2  = (const float*)d_in[27];

    float* ws  = (float*)d_ws;
    short* wsh = (short*)(ws + 4096);
    unsigned* h2p = (unsigned*)(ws + OFF_H2P);
    float* out = (float*)d_out;

    k_tabprep<<<133, 256, 0, stream>>>(tptr, Wt, bt, Wq1, bq1, Wk1, bk1, Wv1, bv1,
                                       Ws1, bs1, Wq2, bq2, Wk2, Wv2, Ws2, We1, Wn,
                                       ws, wsh);
    k_main<<<512, 512, 0, stream>>>(x, ei, ws, wsh, bv2, bs2, h2p);
    k_edge<<<1024, 256, 0, stream>>>(wsh, h2p, bn, be1, We2, be2, out);
}

// Round 9
// 64.016 us; speedup vs baseline: 1.1805x; 1.1805x over previous
//
#include <hip/hip_runtime.h>
#include <math.h>

// Problem constants
constexpr int EPG  = 512;     // edges per graph
constexpr int ETOT = 131072;  // total edges

// ws float-region offsets (floats)
constexpr size_t TAB_Q  = 0;
constexpr size_t TAB_K  = 1024;
constexpr size_t TAB_V  = 2048;
constexpr size_t TAB_S  = 3072;   // 4*64
constexpr size_t TAB_LG = 3328;   // 64
constexpr size_t OFF_H2P = 65536; // packed h2 u32 [16384][64]

// ws short-region offsets (shorts), region starts at (short*)(ws + 4096)
constexpr int PK_V_HI   = 0;      // Wv2^T [256][64]
constexpr int PK_V_LO   = 16384;
constexpr int PK_S_HI   = 32768;  // Ws2^T [64][64]
constexpr int PK_S_LO   = 36864;
constexpr int PK_E1T_HI = 40960;
constexpr int PK_E1T_LO = 45056;
constexpr int PK_E1B_HI = 49152;
constexpr int PK_E1B_LO = 53248;
constexpr int PK_M_HI   = 57344;  // per head +4096: pack[m][k] = M~[k][m]
constexpr int PK_M_LO   = 73728;
constexpr int PK_VV_HI  = 90112;  // [16][64] rows h<4 = v~_h, rest 0
constexpr int PK_VV_LO  = 91136;
constexpr int PK_N_HI   = 92160;  // [16][64] rows c<4 = Wn[:,c], rest 0
constexpr int PK_N_LO   = 93184;

typedef short bf16x8 __attribute__((ext_vector_type(8)));
typedef float f32x4  __attribute__((ext_vector_type(4)));

__device__ __forceinline__ short f2bf(float x) {
    unsigned u = __float_as_uint(x);
    u = (u + 0x7fffu + ((u >> 16) & 1u)) >> 16;   // RNE
    return (short)u;
}
__device__ __forceinline__ float bf2f(short h) {
    return __uint_as_float(((unsigned)(unsigned short)h) << 16);
}
__device__ __forceinline__ void splt(float x, short& hi, short& lo) {
    hi = f2bf(x);
    lo = f2bf(x - bf2f(hi));
}
__device__ __forceinline__ unsigned packsplt(float x) {
    short hi, lo; splt(x, hi, lo);
    return ((unsigned)(unsigned short)hi << 16) | (unsigned short)lo;
}

// hi/lo split product: C += Ah*Bh + Ah*Bl + Al*Bh  (error ~2^-17 rel)
__device__ __forceinline__ f32x4 mfma3(bf16x8 ah, bf16x8 al, bf16x8 bh, bf16x8 bl, f32x4 c) {
    c = __builtin_amdgcn_mfma_f32_16x16x32_bf16(ah, bh, c, 0, 0, 0);
    c = __builtin_amdgcn_mfma_f32_16x16x32_bf16(ah, bl, c, 0, 0, 0);
    c = __builtin_amdgcn_mfma_f32_16x16x32_bf16(al, bh, c, 0, 0, 0);
    return c;
}

// fragment from LDS row-major [.][72] bf16: lane row=base+(l&15), k=kb+(l>>4)*8+e
__device__ __forceinline__ bf16x8 ldsfrag(const short* p, int rowb, int kb, int lane) {
    return *(const bf16x8*)&p[(rowb + (lane & 15)) * 72 + kb + ((lane >> 4) << 3)];
}
// fragment from global pack [N][64] bf16
__device__ __forceinline__ bf16x8 gpfrag(const short* p, int colb, int kb, int lane) {
    return *(const bf16x8*)&p[((colb + (lane & 15)) << 6) + kb + ((lane >> 4) << 3)];
}
// unpack 8 consecutive (hi<<16|lo) u32 -> two bf16x8 fragments
__device__ __forceinline__ void unpack8(const unsigned* p, bf16x8& hv, bf16x8& lv) {
    uint4 a = *(const uint4*)p;
    uint4 b = *(const uint4*)(p + 4);
    unsigned u[8] = {a.x, a.y, a.z, a.w, b.x, b.y, b.z, b.w};
    bf16x8 h, l;
    #pragma unroll
    for (int i = 0; i < 8; i++) { h[i] = (short)(u[i] >> 16); l[i] = (short)(u[i] & 0xffffu); }
    hv = h; lv = l;
}

// ---------------------------------------------------------------------------
// k_tabprep: unchanged from round 8.
// ---------------------------------------------------------------------------
__global__ __launch_bounds__(256) void k_tabprep(
    const int* __restrict__ t_ptr,
    const float* __restrict__ Wt,  const float* __restrict__ bt,
    const float* __restrict__ Wq1, const float* __restrict__ bq1,
    const float* __restrict__ Wk1, const float* __restrict__ bk1,
    const float* __restrict__ Wv1, const float* __restrict__ bv1,
    const float* __restrict__ Ws1, const float* __restrict__ bs1,
    const float* __restrict__ Wq2, const float* __restrict__ bq2,
    const float* __restrict__ Wk2, const float* __restrict__ Wv2,
    const float* __restrict__ Ws2, const float* __restrict__ We1,
    const float* __restrict__ Wn,
    float* __restrict__ ws, short* __restrict__ wsh)
{
    const int t = threadIdx.x, b = blockIdx.x;
    if (b < 112) {
        const float* src; int N; int dhi; int nb;
        if (b < 64)      { src = Wv2;           N = 256; dhi = PK_V_HI;   nb = b; }
        else if (b < 80) { src = Ws2;           N = 64;  dhi = PK_S_HI;   nb = b - 64; }
        else if (b < 96) { src = We1;           N = 64;  dhi = PK_E1T_HI; nb = b - 80; }
        else             { src = We1 + 64 * 64; N = 64;  dhi = PK_E1B_HI; nb = b - 96; }
        int dlo = dhi + N * 64;
        int n = nb * 4 + (t >> 6), kk = t & 63;
        float v = src[(size_t)kk * N + n];
        short hi, lo; splt(v, hi, lo);
        wsh[dhi + n * 64 + kk] = hi;
        wsh[dlo + n * 64 + kk] = lo;
        return;
    }
    if (b < 128) {   // M~ quarter block: head h, m rows m0..m0+16
        int h = (b - 112) >> 2, m0 = ((b - 112) & 3) * 16;
        __shared__ __align__(16) float wq[64][68];
        __shared__ __align__(16) float wk[16][68];
        for (int i = t; i < 1024; i += 256) {
            int r = i >> 4, c4 = (i & 15) * 4;
            *(float4*)&wq[r][c4] = *(const float4*)&Wq2[(size_t)r * 256 + h * 64 + c4];
        }
        {
            int r = t >> 4, c4 = (t & 15) * 4;
            *(float4*)&wk[r][c4] = *(const float4*)&Wk2[(size_t)(m0 + r) * 256 + h * 64 + c4];
        }
        __syncthreads();
        const int m = m0 + (t >> 4), kk0 = (t & 15) * 4;
        const float* wkr = &wk[t >> 4][0];
        for (int kk = kk0; kk < kk0 + 4; kk++) {
            const float* wqr = &wq[kk][0];
            float acc = 0.f;
            #pragma unroll
            for (int a = 0; a < 64; a += 4) {
                float4 qa = *(const float4*)(wqr + a);
                float4 ka = *(const float4*)(wkr + a);
                acc += qa.x * ka.x + qa.y * ka.y + qa.z * ka.z + qa.w * ka.w;
            }
            acc *= 0.125f;
            short hi, lo; splt(acc, hi, lo);
            wsh[PK_M_HI + h * 4096 + m * 64 + kk] = hi;
            wsh[PK_M_LO + h * 4096 + m * 64 + kk] = lo;
        }
        return;
    }
    if (b < 132) {   // v~ = Wk bq /8 per head
        int h = b - 128;
        if (t < 64) {
            float acc = 0.f;
            for (int a = 0; a < 64; a++)
                acc += Wk2[(size_t)t * 256 + h * 64 + a] * bq2[h * 64 + a];
            short hi, lo; splt(0.125f * acc, hi, lo);
            wsh[PK_VV_HI + h * 64 + t] = hi;
            wsh[PK_VV_LO + h * 64 + t] = lo;
        }
        return;
    }
    // tables path
    __shared__ float se[16], temb[16];
    __shared__ float q1t[4][256], k1t[4][256], v1t[4][256], s1t[4][64];
    if (t < 8) {
        float tv = (float)(*t_ptr) * 0.01f;
        float scale = logf(10000.0f) / 7.0f;
        float e = tv * expf(-(float)t * scale);
        se[t]     = sinf(e);
        se[t + 8] = cosf(e);
    }
    __syncthreads();
    if (t < 16) {
        float acc = bt[t];
        for (int i = 0; i < 16; i++) acc += se[i] * Wt[i * 16 + t];
        temb[t] = acc;
    }
    __syncthreads();
    {
        const int o = t;
        float tq = 0.f, tk = 0.f, tv = 0.f;
        for (int d = 0; d < 16; d++) {
            float td = temb[d];
            tq += td * Wq1[(4 + d) * 256 + o];
            tk += td * Wk1[(4 + d) * 256 + o];
            tv += td * Wv1[(4 + d) * 256 + o];
        }
        for (int c = 0; c < 4; c++) {
            q1t[c][o] = Wq1[c * 256 + o] + tq + bq1[o];
            k1t[c][o] = Wk1[c * 256 + o] + tk + bk1[o];
            v1t[c][o] = Wv1[c * 256 + o] + tv + bv1[o];
        }
        if (o < 64) {
            float ts = 0.f;
            for (int d = 0; d < 16; d++) ts += temb[d] * Ws1[(4 + d) * 64 + o];
            for (int c = 0; c < 4; c++) s1t[c][o] = Ws1[c * 64 + o] + ts + bs1[o];
        }
    }
    __syncthreads();
    for (int idx = t; idx < 1024; idx += 256) {
        int c = idx >> 8, o = idx & 255;
        ws[TAB_Q + idx] = q1t[c][o];
        ws[TAB_K + idx] = k1t[c][o];
        ws[TAB_V + idx] = v1t[c][o];
    }
    ws[TAB_S + t] = s1t[t >> 6][t & 63];
    if (t < 64) {
        int cd = t >> 4, cs = (t >> 2) & 3, h = t & 3;
        float acc = 0.f;
        for (int d = 0; d < 64; d++) acc += q1t[cd][h * 64 + d] * k1t[cs][h * 64 + d];
        ws[TAB_LG + t] = acc * 0.125f;
    }
    for (int idx = t; idx < 1024; idx += 256) {
        int c = idx >> 6, k = idx & 63;
        float v = (c < 4) ? Wn[k * 4 + c] : 0.f;
        short hi, lo; splt(v, hi, lo);
        wsh[PK_N_HI + idx] = hi;
        wsh[PK_N_LO + idx] = lo;
    }
    for (int idx = 256 + t; idx < 1024; idx += 256) {
        wsh[PK_VV_HI + idx] = 0;
        wsh[PK_VV_LO + idx] = 0;
    }
}

// ---------------------------------------------------------------------------
// k_main: grid 1024 = (graph, 16-row quarter), 256 thr = 4 waves. Wave w owns
// head w end-to-end with private LDS regions: R1 = G -> U, R2 = S -> PV(f32);
// P stays in registers (softmax lane layout == A-frag layout). PV = (P.h1).Wv^T
// via h1^T (built once). Only 4 block barriers total; the whole attention is
// wave-private (same-wave LDS RAW ordered by lgkmcnt, no __syncthreads).
// LDS 77.4 KB -> 2 blocks/CU; plain bounds => compiler sees 2 waves/SIMD cap
// and uses a full VGPR budget (no spill).
// ---------------------------------------------------------------------------
__global__ __launch_bounds__(256) void k_main(
    const float* __restrict__ x, const int* __restrict__ ei,
    const float* __restrict__ ws, const short* __restrict__ wsh,
    const float* __restrict__ bv, const float* __restrict__ bsk,
    unsigned* __restrict__ h2p)
{
    __shared__ __align__(16) char smem[77376];
    short* hHi = (short*)(smem);              // h1  [64][72]
    short* hLo = (short*)(smem + 9216);
    short* tHi = (short*)(smem + 18432);      // h1^T [feat][72] (cols = node)
    short* tLo = (short*)(smem + 27648);
    // per-wave R1 (4608 B each): G hi/lo [16][72] -> U hi/lo [16][72]
    // per-wave R2 (4608 B each): S f32 [16][68]  -> PV f32 [16][68]
    char*  R1base = smem + 36864;
    char*  R2base = smem + 55296;
    char*  Cc     = smem + 73728;             // [16][68] u8 counts
    float* wcolb  = (float*)(smem + 74816);   // [4][64]
    float* lgs    = (float*)(smem + 75840);   // 64
    int*   cls    = (int*)(smem + 76096);     // 64
    int*   cnt4   = (int*)(smem + 76352);     // [64][4]
    // setup aliases over R1 region (dead until wave phases)
    float* v1t    = (float*)(smem + 36864);   // 1024
    float* s1t    = (float*)(smem + 40960);   // 256

    const int g    = blockIdx.x >> 2;
    const int i0   = (blockIdx.x & 3) * 16;   // this block's 16 q-rows
    const int t    = threadIdx.x;
    const int lane = t & 63, w = t >> 6;      // wave = head
    const int lg4  = ((lane >> 4) << 2);
    const int lg8  = ((lane >> 4) << 3);
    const int l15  = lane & 15;

    short* GHi = (short*)(R1base + w * 4608);      // also U
    short* GLo = (short*)(R1base + w * 4608 + 2304);
    float* Sf  = (float*)(R2base + w * 4608);      // also PV

    // ---- P0: tables + zero counters ---------------------------------------
    for (int i = t; i < 1024; i += 256) v1t[i] = ws[TAB_V + i];
    s1t[t] = ws[TAB_S + t];
    if (t < 64)  lgs[t] = ws[TAB_LG + t];
    if (t < 64) {
        const float* xr = x + (size_t)(g * 64 + t) * 4;
        int c = 0;
        if (xr[1] > 0.5f) c = 1;
        if (xr[2] > 0.5f) c = 2;
        if (xr[3] > 0.5f) c = 3;
        cls[t] = c;
    }
    cnt4[t] = 0;
    for (int i = t; i < 272; i += 256) ((int*)Cc)[i] = 0;
    __syncthreads();   // B0

    // ---- P1: edge counts ---------------------------------------------------
    for (int e = t; e < EPG; e += 256) {
        int ge = g * EPG + e;
        int ls = ei[ge] - g * 64;
        int ld = ei[ETOT + ge] - g * 64;
        atomicAdd(&cnt4[ld * 4 + cls[ls]], 1);
        int lr = ld - i0;
        if ((unsigned)lr < 16u) {
            int idx = lr * 68 + ls;
            atomicAdd((int*)(Cc + (idx & ~3)), 1 << ((idx & 3) * 8));
        }
    }
    __syncthreads();   // B1

    // ---- P2: h1 (full graph, inline alpha) + h1^T ---------------------------
    {
        const int row = t >> 2, d0 = (t & 3) * 16;
        int cd = cls[row];
        int c0 = cnt4[row * 4], c1 = cnt4[row * 4 + 1],
            c2 = cnt4[row * 4 + 2], c3 = cnt4[row * 4 + 3];
        float a[16];
        #pragma unroll
        for (int hh = 0; hh < 4; hh++) {
            float l0 = lgs[cd * 16 + hh], l1 = lgs[cd * 16 + 4 + hh],
                  l2 = lgs[cd * 16 + 8 + hh], l3 = lgs[cd * 16 + 12 + hh];
            float m = -1e30f;
            if (c0 > 0) m = fmaxf(m, l0);
            if (c1 > 0) m = fmaxf(m, l1);
            if (c2 > 0) m = fmaxf(m, l2);
            if (c3 > 0) m = fmaxf(m, l3);
            float e0 = (c0 > 0) ? (float)c0 * __expf(l0 - m) : 0.f;
            float e1 = (c1 > 0) ? (float)c1 * __expf(l1 - m) : 0.f;
            float e2 = (c2 > 0) ? (float)c2 * __expf(l2 - m) : 0.f;
            float e3 = (c3 > 0) ? (float)c3 * __expf(l3 - m) : 0.f;
            float den = e0 + e1 + e2 + e3;
            float inv = (den > 0.f) ? 0.25f / den : 0.f;
            a[hh * 4 + 0] = e0 * inv; a[hh * 4 + 1] = e1 * inv;
            a[hh * 4 + 2] = e2 * inv; a[hh * 4 + 3] = e3 * inv;
        }
        bf16x8 vh0, vl0, vh1, vl1;
        #pragma unroll
        for (int jj = 0; jj < 16; jj++) {
            int d = d0 + jj;
            float acc = s1t[cd * 64 + d];
            #pragma unroll
            for (int hh = 0; hh < 4; hh++)
                #pragma unroll
                for (int c = 0; c < 4; c++)
                    acc += a[hh * 4 + c] * v1t[c * 256 + hh * 64 + d];
            float o = fmaxf(acc, 0.f);
            short hi, lo; splt(o, hi, lo);
            if (jj < 8) { vh0[jj] = hi; vl0[jj] = lo; }
            else        { vh1[jj - 8] = hi; vl1[jj - 8] = lo; }
            tHi[d * 72 + row] = hi;
            tLo[d * 72 + row] = lo;
        }
        *(bf16x8*)&hHi[row * 72 + d0]     = vh0;
        *(bf16x8*)&hLo[row * 72 + d0]     = vl0;
        *(bf16x8*)&hHi[row * 72 + d0 + 8] = vh1;
        *(bf16x8*)&hLo[row * 72 + d0 + 8] = vl1;
    }
    __syncthreads();   // B2 — h1/h1T ready; everything below is wave-private

    const int h = w;   // this wave's head

    // ---- cached h1 A-frags (our 16 q-rows) ---------------------------------
    bf16x8 AhQ0 = ldsfrag(hHi, i0, 0, lane),  AhQ1 = ldsfrag(hHi, i0, 32, lane);
    bf16x8 AlQ0 = ldsfrag(hLo, i0, 0, lane),  AlQ1 = ldsfrag(hLo, i0, 32, lane);

    // ---- skip projection (d-quarter w*16, kept in regs) --------------------
    f32x4 skacc = {0.f, 0.f, 0.f, 0.f};
    {
        int cb = w * 16;
        skacc = mfma3(AhQ0, AlQ0, gpfrag(wsh + PK_S_HI, cb, 0, lane),
                                   gpfrag(wsh + PK_S_LO, cb, 0, lane), skacc);
        skacc = mfma3(AhQ1, AlQ1, gpfrag(wsh + PK_S_HI, cb, 32, lane),
                                   gpfrag(wsh + PK_S_LO, cb, 32, lane), skacc);
        float bb = bsk[cb + l15];
        #pragma unroll
        for (int r = 0; r < 4; r++) skacc[r] += bb;
    }

    // ---- wcol for this head via MFMA: C[j][slot], keep slot==h -------------
    {
        bf16x8 vv0h = gpfrag(wsh + PK_VV_HI, 0, 0, lane);
        bf16x8 vv0l = gpfrag(wsh + PK_VV_LO, 0, 0, lane);
        bf16x8 vv1h = gpfrag(wsh + PK_VV_HI, 0, 32, lane);
        bf16x8 vv1l = gpfrag(wsh + PK_VV_LO, 0, 32, lane);
        #pragma unroll
        for (int jb = 0; jb < 64; jb += 16) {
            f32x4 wc = {0.f, 0.f, 0.f, 0.f};
            wc = mfma3(ldsfrag(hHi, jb, 0, lane),  ldsfrag(hLo, jb, 0, lane),  vv0h, vv0l, wc);
            wc = mfma3(ldsfrag(hHi, jb, 32, lane), ldsfrag(hLo, jb, 32, lane), vv1h, vv1l, wc);
            if (l15 == h) {
                #pragma unroll
                for (int r = 0; r < 4; r++) wcolb[h * 64 + jb + lg4 + r] = wc[r];
            }
        }
    }

    // ---- G = h1_local . M~_h^T  -> R1 (hi/lo) ------------------------------
    {
        const short* pmh = wsh + PK_M_HI + h * 4096;
        const short* pml = wsh + PK_M_LO + h * 4096;
        #pragma unroll
        for (int mb = 0; mb < 64; mb += 16) {
            f32x4 ga = {0.f, 0.f, 0.f, 0.f};
            ga = mfma3(AhQ0, AlQ0, gpfrag(pmh, mb, 0, lane),  gpfrag(pml, mb, 0, lane),  ga);
            ga = mfma3(AhQ1, AlQ1, gpfrag(pmh, mb, 32, lane), gpfrag(pml, mb, 32, lane), ga);
            #pragma unroll
            for (int r = 0; r < 4; r++) {
                short hi, lo; splt(ga[r], hi, lo);
                GHi[(lg4 + r) * 72 + mb + l15] = hi;
                GLo[(lg4 + r) * 72 + mb + l15] = lo;
            }
        }
    }

    // ---- S = G . h1^T_j  -> R2 (f32) ---------------------------------------
    {
        bf16x8 g0h = ldsfrag(GHi, 0, 0, lane),  g0l = ldsfrag(GLo, 0, 0, lane);
        bf16x8 g1h = ldsfrag(GHi, 0, 32, lane), g1l = ldsfrag(GLo, 0, 32, lane);
        #pragma unroll
        for (int jb = 0; jb < 64; jb += 16) {
            f32x4 s = {0.f, 0.f, 0.f, 0.f};
            s = mfma3(g0h, g0l, ldsfrag(hHi, jb, 0, lane),  ldsfrag(hLo, jb, 0, lane),  s);
            s = mfma3(g1h, g1l, ldsfrag(hHi, jb, 32, lane), ldsfrag(hLo, jb, 32, lane), s);
            #pragma unroll
            for (int r = 0; r < 4; r++)
                Sf[(lg4 + r) * 68 + jb + l15] = s[r];
        }
    }

    // ---- softmax (lane: row=l15, j = lg8..+8 and 32+lg8..+8) -> P in regs --
    bf16x8 pa0h, pa0l, pa1h, pa1l;
    {
        const int lr = l15;
        float sv[16];
        {
            const float* sp = Sf + lr * 68;
            float4 a0 = *(const float4*)(sp + lg8);
            float4 a1 = *(const float4*)(sp + lg8 + 4);
            float4 a2 = *(const float4*)(sp + 32 + lg8);
            float4 a3 = *(const float4*)(sp + 32 + lg8 + 4);
            sv[0]=a0.x; sv[1]=a0.y; sv[2]=a0.z; sv[3]=a0.w;
            sv[4]=a1.x; sv[5]=a1.y; sv[6]=a1.z; sv[7]=a1.w;
            sv[8]=a2.x; sv[9]=a2.y; sv[10]=a2.z; sv[11]=a2.w;
            sv[12]=a3.x; sv[13]=a3.y; sv[14]=a3.z; sv[15]=a3.w;
        }
        int cv[16];
        {
            const unsigned* crow = (const unsigned*)(Cc + lr * 68);
            unsigned c0 = crow[lg8 >> 2], c1 = crow[(lg8 >> 2) + 1];
            unsigned c2 = crow[(32 + lg8) >> 2], c3 = crow[((32 + lg8) >> 2) + 1];
            #pragma unroll
            for (int e = 0; e < 4; e++) {
                cv[e]      = (c0 >> (e * 8)) & 255;
                cv[4 + e]  = (c1 >> (e * 8)) & 255;
                cv[8 + e]  = (c2 >> (e * 8)) & 255;
                cv[12 + e] = (c3 >> (e * 8)) & 255;
            }
        }
        #pragma unroll
        for (int e = 0; e < 8; e++) {
            sv[e]     += wcolb[h * 64 + lg8 + e];
            sv[8 + e] += wcolb[h * 64 + 32 + lg8 + e];
        }
        float m = -1e30f;
        #pragma unroll
        for (int e = 0; e < 16; e++) if (cv[e] > 0) m = fmaxf(m, sv[e]);
        m = fmaxf(m, __shfl_xor(m, 16));
        m = fmaxf(m, __shfl_xor(m, 32));
        float den = 0.f; float p[16];
        #pragma unroll
        for (int e = 0; e < 16; e++) {
            p[e] = (cv[e] > 0) ? (float)cv[e] * __expf(sv[e] - m) : 0.f;
            den += p[e];
        }
        den += __shfl_xor(den, 16);
        den += __shfl_xor(den, 32);
        float inv = (den > 0.f) ? 1.f / den : 0.f;
        #pragma unroll
        for (int e = 0; e < 8; e++) {
            short hi, lo;
            splt(p[e] * inv, hi, lo);      pa0h[e] = hi; pa0l[e] = lo;
            splt(p[8 + e] * inv, hi, lo);  pa1h[e] = hi; pa1l[e] = lo;
        }
    }

    // ---- U = P . h1  -> R1 (over G, hi/lo) ---------------------------------
    #pragma unroll
    for (int fb = 0; fb < 64; fb += 16) {
        f32x4 u = {0.f, 0.f, 0.f, 0.f};
        u = mfma3(pa0h, pa0l, ldsfrag(tHi, fb, 0, lane),  ldsfrag(tLo, fb, 0, lane),  u);
        u = mfma3(pa1h, pa1l, ldsfrag(tHi, fb, 32, lane), ldsfrag(tLo, fb, 32, lane), u);
        #pragma unroll
        for (int r = 0; r < 4; r++) {
            short hi, lo; splt(u[r], hi, lo);
            GHi[(lg4 + r) * 72 + fb + l15] = hi;
            GLo[(lg4 + r) * 72 + fb + l15] = lo;
        }
    }

    // ---- PV = U . Wv_h^T  -> R2 (f32, over S) ------------------------------
    {
        bf16x8 u0h = ldsfrag(GHi, 0, 0, lane),  u0l = ldsfrag(GLo, 0, 0, lane);
        bf16x8 u1h = ldsfrag(GHi, 0, 32, lane), u1l = ldsfrag(GLo, 0, 32, lane);
        #pragma unroll
        for (int db = 0; db < 64; db += 16) {
            int gc = h * 64 + db;
            f32x4 pv = {0.f, 0.f, 0.f, 0.f};
            pv = mfma3(u0h, u0l, gpfrag(wsh + PK_V_HI, gc, 0, lane),
                                  gpfrag(wsh + PK_V_LO, gc, 0, lane), pv);
            pv = mfma3(u1h, u1l, gpfrag(wsh + PK_V_HI, gc, 32, lane),
                                  gpfrag(wsh + PK_V_LO, gc, 32, lane), pv);
            #pragma unroll
            for (int r = 0; r < 4; r++)
                Sf[(lg4 + r) * 68 + db + l15] = pv[r];
        }
    }
    __syncthreads();   // B3 — all heads' PV ready

    // ---- combine: h2 = relu(0.25*(Sum_h PV_h + Sum_h bv_h) + skip) ---------
    {
        const int d = w * 16 + l15;
        float bvsum = bv[d] + bv[64 + d] + bv[128 + d] + bv[192 + d];
        #pragma unroll
        for (int r = 0; r < 4; r++) {
            float sum = 0.f;
            #pragma unroll
            for (int hh = 0; hh < 4; hh++)
                sum += ((const float*)(R2base + hh * 4608))[(lg4 + r) * 68 + d];
            float v = fmaxf(0.25f * (sum + bvsum) + skacc[r], 0.f);
            h2p[(size_t)(g * 64 + i0 + lg4 + r) * 64 + d] = packsplt(v);
        }
    }
}

// ---------------------------------------------------------------------------
// k_edge: unchanged from round 8.
// ---------------------------------------------------------------------------
__global__ __launch_bounds__(256) void k_edge(
    const short* __restrict__ wsh, const unsigned* __restrict__ h2g,
    const float* __restrict__ bn, const float* __restrict__ be1,
    const float* __restrict__ We2, const float* __restrict__ be2,
    float* __restrict__ out)
{
    __shared__ __align__(16) char smem[39680];
    unsigned* h2P = (unsigned*)(smem);           // [64][68] packed
    float*    Af  = (float*)(smem + 17408);      // [16][68]
    float*    BTf = (float*)(smem + 21760);      // [64][68]
    float*    w2s = (float*)(smem + 39168);      // 128

    const int g  = blockIdx.x >> 2;
    const int i0 = (blockIdx.x & 3) * 16;
    const int t  = threadIdx.x;
    const int lane = t & 63, w = t >> 6;
    const int lg4 = ((lane >> 4) << 2);
    const int lg8 = ((lane >> 4) << 3);
    const int l15 = lane & 15;

    {
        int row = t >> 2, c16 = (t & 3) * 16;
        const unsigned* src = h2g + (size_t)(g * 64 + row) * 64 + c16;
        #pragma unroll
        for (int q = 0; q < 4; q++)
            *(uint4*)&h2P[row * 68 + c16 + q * 4] = *(const uint4*)(src + q * 4);
    }
    if (t < 128) w2s[(t & 1) * 64 + (t >> 1)] = We2[t];
    __syncthreads();

    {
        bf16x8 aq0, lq0, aq1, lq1;
        const unsigned* ap = h2P + (i0 + l15) * 68;
        unpack8(ap + lg8, aq0, lq0);
        unpack8(ap + 32 + lg8, aq1, lq1);
        {
            int colb = w * 16;
            bf16x8 e0h = gpfrag(wsh + PK_E1T_HI, colb, 0, lane),  e0l = gpfrag(wsh + PK_E1T_LO, colb, 0, lane);
            bf16x8 e1h = gpfrag(wsh + PK_E1T_HI, colb, 32, lane), e1l = gpfrag(wsh + PK_E1T_LO, colb, 32, lane);
            f32x4 aa = {0.f, 0.f, 0.f, 0.f};
            aa = mfma3(aq0, lq0, e0h, e0l, aa);
            aa = mfma3(aq1, lq1, e1h, e1l, aa);
            float bev = be1[colb + l15];
            #pragma unroll
            for (int r = 0; r < 4; r++)
                Af[(lg4 + r) * 68 + colb + l15] = aa[r] + bev;
        }
        if (w == 0) {
            bf16x8 n0h = gpfrag(wsh + PK_N_HI, 0, 0, lane),  n0l = gpfrag(wsh + PK_N_LO, 0, 0, lane);
            bf16x8 n1h = gpfrag(wsh + PK_N_HI, 0, 32, lane), n1l = gpfrag(wsh + PK_N_LO, 0, 32, lane);
            f32x4 nl = {0.f, 0.f, 0.f, 0.f};
            nl = mfma3(aq0, lq0, n0h, n0l, nl);
            nl = mfma3(aq1, lq1, n1h, n1l, nl);
            if (l15 < 4) {
                #pragma unroll
                for (int r = 0; r < 4; r++)
                    out[(size_t)(g * 64 + i0 + lg4 + r) * 4 + l15] = nl[r] + bn[l15];
            }
        }
    }
    {
        bf16x8 af0, lf0, af1, lf1;
        const unsigned* ap = h2P + (w * 16 + l15) * 68;
        unpack8(ap + lg8, af0, lf0);
        unpack8(ap + 32 + lg8, af1, lf1);
        #pragma unroll
        for (int ct = 0; ct < 4; ct++) {
            int colb = ct * 16;
            bf16x8 b0h = gpfrag(wsh + PK_E1B_HI, colb, 0, lane),  b0l = gpfrag(wsh + PK_E1B_LO, colb, 0, lane);
            bf16x8 b1h = gpfrag(wsh + PK_E1B_HI, colb, 32, lane), b1l = gpfrag(wsh + PK_E1B_LO, colb, 32, lane);
            f32x4 bb = {0.f, 0.f, 0.f, 0.f};
            bb = mfma3(af0, lf0, b0h, b0l, bb);
            bb = mfma3(af1, lf1, b1h, b1l, bb);
            #pragma unroll
            for (int r = 0; r < 4; r++)
                BTf[(colb + l15) * 68 + w * 16 + lg4 + r] = bb[r];
        }
    }
    __syncthreads();

    {
        const int j = t & 63;
        float e0[4], e1[4];
        const float cb0 = be2[0], cb1 = be2[1];
        #pragma unroll
        for (int ii = 0; ii < 4; ii++) { e0[ii] = cb0; e1[ii] = cb1; }
        for (int kb = 0; kb < 4; kb++) {
            const int k0 = kb * 16;
            float bj[16], wa[16], wb[16];
            #pragma unroll
            for (int q = 0; q < 16; q++) {
                bj[q] = BTf[(k0 + q) * 68 + j];
                wa[q] = w2s[k0 + q];
                wb[q] = w2s[64 + k0 + q];
            }
            #pragma unroll
            for (int ii = 0; ii < 4; ii++) {
                const float* ar = &Af[(w * 4 + ii) * 68 + k0];
                #pragma unroll
                for (int q = 0; q < 16; q += 4) {
                    float4 a4 = *(const float4*)(ar + q);
                    float s;
                    s = fmaxf(a4.x + bj[q + 0], 0.f); e0[ii] += s * wa[q + 0]; e1[ii] += s * wb[q + 0];
                    s = fmaxf(a4.y + bj[q + 1], 0.f); e0[ii] += s * wa[q + 1]; e1[ii] += s * wb[q + 1];
                    s = fmaxf(a4.z + bj[q + 2], 0.f); e0[ii] += s * wa[q + 2]; e1[ii] += s * wb[q + 2];
                    s = fmaxf(a4.w + bj[q + 3], 0.f); e0[ii] += s * wa[q + 3]; e1[ii] += s * wb[q + 3];
                }
            }
        }
        float2* oe = (float2*)(out + 65536);
        #pragma unroll
        for (int ii = 0; ii < 4; ii++)
            oe[(size_t)(g * 64 + i0 + w * 4 + ii) * 64 + j] = make_float2(e0[ii], e1[ii]);
    }
}

// ---------------------------------------------------------------------------
extern "C" void kernel_launch(void* const* d_in, const int* in_sizes, int n_in,
                              void* d_out, int out_size, void* d_ws, size_t ws_size,
                              hipStream_t stream)
{
    const float* x    = (const float*)d_in[0];
    const int*   ei   = (const int*)d_in[1];
    const int*   tptr = (const int*)d_in[3];
    const float* Wt   = (const float*)d_in[4];
    const float* bt   = (const float*)d_in[5];
    const float* Wq1  = (const float*)d_in[6];
    const float* bq1  = (const float*)d_in[7];
    const float* Wk1  = (const float*)d_in[8];
    const float* bk1  = (const float*)d_in[9];
    const float* Wv1  = (const float*)d_in[10];
    const float* bv1  = (const float*)d_in[11];
    const float* Ws1  = (const float*)d_in[12];
    const float* bs1  = (const float*)d_in[13];
    const float* Wq2  = (const float*)d_in[14];
    const float* bq2  = (const float*)d_in[15];
    const float* Wk2  = (const float*)d_in[16];
    const float* Wv2  = (const float*)d_in[18];
    const float* bv2  = (const float*)d_in[19];
    const float* Ws2  = (const float*)d_in[20];
    const float* bs2  = (const float*)d_in[21];
    const float* Wn   = (const float*)d_in[22];
    const float* bn   = (const float*)d_in[23];
    const float* We1  = (const float*)d_in[24];
    const float* be1  = (const float*)d_in[25];
    const float* We2  = (const float*)d_in[26];
    const float* be2  = (const float*)d_in[27];

    float* ws  = (float*)d_ws;
    short* wsh = (short*)(ws + 4096);
    unsigned* h2p = (unsigned*)(ws + OFF_H2P);
    float* out = (float*)d_out;

    k_tabprep<<<133, 256, 0, stream>>>(tptr, Wt, bt, Wq1, bq1, Wk1, bk1, Wv1, bv1,
                                       Ws1, bs1, Wq2, bq2, Wk2, Wv2, Ws2, We1, Wn,
                                       ws, wsh);
    k_main<<<1024, 256, 0, stream>>>(x, ei, ws, wsh, bv2, bs2, h2p);
    k_edge<<<1024, 256, 0, stream>>>(wsh, h2p, bn, be1, We2, be2, out);
}